// Round 7
// baseline (359.621 us; speedup 1.0000x reference)
//
#include <hip/hip_runtime.h>
#include <stdint.h>

#define B_   4
#define T_   32
#define N_   4096
#define F_   16
#define G_   64      // B*F
#define M_   128
#define K_   32
#define C0_  64
#define C1_  128

typedef short  short8 __attribute__((ext_vector_type(8)));
typedef float  f32x4  __attribute__((ext_vector_type(4)));

static __device__ __forceinline__ short f2bf(float x) {
    union { float f; unsigned u; } v; v.f = x;
    unsigned r = (v.u + 0x7FFFu + ((v.u >> 16) & 1u)) >> 16;
    return (short)r;
}
static __device__ __forceinline__ float bf2f(short h) {
    union { float f; unsigned u; } v; v.u = ((unsigned)(unsigned short)h) << 16;
    return v.f;
}

// u64 move via DPP (both 32b halves), old=0. A zero result (invalid source
// lane) is identity for our max-combine: real keys never lose to 0 via
// strict '>', so bcast15/bcast31's unfed lanes are harmless.
template<int CTRL>
static __device__ __forceinline__ unsigned long long dpp_u64(unsigned long long v) {
    int lo = __builtin_amdgcn_update_dpp(0, (int)(unsigned)v,         CTRL, 0xF, 0xF, false);
    int hi = __builtin_amdgcn_update_dpp(0, (int)(unsigned)(v >> 32), CTRL, 0xF, 0xF, false);
    return ((unsigned long long)(unsigned)hi << 32) | (unsigned)lo;
}
template<int CTRL>
static __device__ __forceinline__ float dpp_f32(float v) {
    return __int_as_float(__builtin_amdgcn_update_dpp(0, __float_as_int(v), CTRL, 0xF, 0xF, false));
}

// max-combine (key, coords) with DPP-shifted partner. All VALU.
template<int CTRL>
static __device__ __forceinline__ void dpp_combine(unsigned long long& key,
                                                   float& cx, float& cy, float& cz) {
    unsigned long long k2 = dpp_u64<CTRL>(key);
    float ox = dpp_f32<CTRL>(cx);
    float oy = dpp_f32<CTRL>(cy);
    float oz = dpp_f32<CTRL>(cz);
    if (k2 > key) { key = k2; cx = ox; cy = oy; cz = oz; }
}

// ---------------------------------------------------------------------------
// Kernel 1: FPS (blocks 0..63, 1024 thr) + Wm hi/lo split (block 64).
// FPS: 16 waves (4/SIMD), 4 pts/thread. Per iter:
//   dist update (4 pts) -> pack u64 key -> extract candidate coords ->
//   all-VALU wave reduce: quad xor1,xor2 + row_ror 4,8 (row max, coords ride
//   along) + row_bcast15 + row_bcast31 (lane 63 = wave max) ->
//   lane 63 publishes (key, xyz) -> ONE barrier ->
//   lanes read entry (lane&15) (per-lane ds_read) + 4 DPP row steps ->
//   every lane holds block max + coords. No coord cache, no dependent fetch.
// Bit-exact fp32 (contract off, reference eval order); key
// (bits(d)<<32)|(4095-i): strict max == first-occurrence argmax.
// ---------------------------------------------------------------------------
__global__ __launch_bounds__(1024) void fps_kernel(const float* __restrict__ xyzs,
                                                   float* __restrict__ anchors,
                                                   float* __restrict__ out_xyz,
                                                   const float* __restrict__ Wm,
                                                   short* __restrict__ Bhi_g,
                                                   short* __restrict__ Blo_g)
{
#pragma clang fp contract(off)
    if (blockIdx.x >= G_) {
        // ---- Wm split role: 1 block x 1024 threads = 1024 tasks ----
        int id = threadIdx.x;
        int o = id >> 3, c = id & 7;
        const float* wp = Wm + o * C0_ + c * 8;
        short8 hv, lv;
#pragma unroll
        for (int e = 0; e < 8; ++e) {
            float v = wp[e];
            short h = f2bf(v);
            short l = f2bf(v - bf2f(h));
            hv[e] = h; lv[e] = l;
        }
        int dst = o * C0_ + c * 8;
        *reinterpret_cast<short8*>(&Bhi_g[dst]) = hv;
        *reinterpret_cast<short8*>(&Blo_g[dst]) = lv;
        return;
    }

    const int g = blockIdx.x;
    const int b = g >> 4, f = g & 15;
    const float* base = xyzs + ((size_t)(b * T_ + 2 * f) * N_) * 3;
    const int t = threadIdx.x;       // 0..1023
    const int lane = t & 63;
    const int wid = t >> 6;          // 0..15

    __shared__ unsigned long long skey[2][16];
    __shared__ __align__(16) float4 scrd[2][16];

    float x[4], y[4], z[4], dist[4];
#pragma unroll
    for (int j = 0; j < 4; ++j) {
        int p = j * 1024 + t;
        x[j] = base[p * 3 + 0];
        y[j] = base[p * 3 + 1];
        z[j] = base[p * 3 + 2];
        dist[j] = 1e10f;
    }

    float px = base[0], py = base[1], pz = base[2];   // anchor 0 = point 0
    float rx = 0.f, ry = 0.f, rz = 0.f;               // my buffered anchor
    if (t == 0) { rx = px; ry = py; rz = pz; }

    for (int it = 1; it < M_; ++it) {
        float bd = -1.0f; int bi = 0;
#pragma unroll
        for (int j = 0; j < 4; ++j) {
            float dx = x[j] - px;
            float dy = y[j] - py;
            float dz = z[j] - pz;
            float d = dx * dx + dy * dy;    // contract off: plain mul/add
            d = d + dz * dz;
            float nd = fminf(dist[j], d);
            dist[j] = nd;
            if (nd > bd) { bd = nd; bi = j * 1024 + t; }  // ascending p: first max kept
        }
        unsigned long long key =
            ((unsigned long long)__float_as_uint(bd) << 32) | (unsigned)(N_ - 1 - bi);
        // candidate coords for my best point
        float cx = x[0], cy = y[0], cz = z[0];
#pragma unroll
        for (int j = 1; j < 4; ++j) {
            if (bi == j * 1024 + t) { cx = x[j]; cy = y[j]; cz = z[j]; }
        }
        // all-VALU wave reduce, coords riding along
        dpp_combine<0xB1>(key, cx, cy, cz);    // quad_perm xor1
        dpp_combine<0x4E>(key, cx, cy, cz);    // quad_perm xor2
        dpp_combine<0x124>(key, cx, cy, cz);   // row_ror:4
        dpp_combine<0x128>(key, cx, cy, cz);   // row_ror:8  -> row max, all 16 lanes
        dpp_combine<0x142>(key, cx, cy, cz);   // row_bcast15 -> row1+=row0, row2+=row1, row3+=row2
        dpp_combine<0x143>(key, cx, cy, cz);   // row_bcast31 -> rows 2,3 += max(row0,row1)
        const int par = it & 1;
        if (lane == 63) {                      // lane 63 holds the wave max
            skey[par][wid] = key;
            scrd[par][wid] = make_float4(cx, cy, cz, 0.f);
        }
        __syncthreads();
        // cross-wave combine: per-lane entry read + 4 DPP row steps
        unsigned long long ck = skey[par][lane & 15];
        float4 cc4 = scrd[par][lane & 15];
        float kx = cc4.x, ky = cc4.y, kz = cc4.z;
        dpp_combine<0xB1>(ck, kx, ky, kz);
        dpp_combine<0x4E>(ck, kx, ky, kz);
        dpp_combine<0x124>(ck, kx, ky, kz);
        dpp_combine<0x128>(ck, kx, ky, kz);    // all lanes: block max + coords
        px = kx; py = ky; pz = kz;
        if (t == it) { rx = px; ry = py; rz = pz; }
    }

    if (t < M_) {
        size_t ao = ((size_t)g * M_ + t) * 3;
        anchors[ao + 0] = rx; anchors[ao + 1] = ry; anchors[ao + 2] = rz;
        out_xyz[ao + 0] = rx; out_xyz[ao + 1] = ry; out_xyz[ao + 2] = rz;
    }
}

// ---------------------------------------------------------------------------
// Kernel 2: Ball query, chunked. One wave per (g, dt, m). 8 iterations' loads
// + ballots issued together (pipelined), then VALU-only prefix-pack; exit
// check per chunk. Semantics identical to first-K-in-radius + fill.
// ---------------------------------------------------------------------------
__global__ __launch_bounds__(256) void ballq_kernel(const float* __restrict__ xyzs,
                                                    const float* __restrict__ anchors,
                                                    int* __restrict__ widx)
{
#pragma clang fp contract(off)
    const float R2 = 0.0225f;
    const int wave = (blockIdx.x << 2) + (threadIdx.x >> 6);
    const int lane = threadIdx.x & 63;
    const int m   = wave % M_;
    const int gd  = wave / M_;      // g*3 + dti
    const int dti = gd % 3;
    const int g   = gd / 3;
    const int b = g >> 4, f = g & 15;
    int tn = 2 * f + dti - 1;
    if (tn < 0) tn = 0;
    const float* nb = xyzs + ((size_t)(b * T_ + tn) * N_) * 3;
    const float* aw = anchors + ((size_t)g * M_ + m) * 3;
    const float ax = aw[0], ay = aw[1], az = aw[2];

    __shared__ int sbuf[4][K_];
    int* buf = sbuf[threadIdx.x >> 6];
    const unsigned long long lanebit = 1ULL << lane;

    int filled = 0;
    for (int cb = 0; cb < 8 && filled < K_; ++cb) {
        unsigned long long mk[8];
#pragma unroll
        for (int u = 0; u < 8; ++u) {
            int p = cb * 512 + u * 64 + lane;
            float dx = nb[p * 3 + 0] - ax;
            float dy = nb[p * 3 + 1] - ay;
            float dz = nb[p * 3 + 2] - az;
            float d2 = dx * dx + dy * dy;
            d2 = d2 + dz * dz;
            mk[u] = __ballot(d2 < R2);
        }
#pragma unroll
        for (int u = 0; u < 8; ++u) {
            if (mk[u] & lanebit) {
                int slot = filled + __popcll(mk[u] & (lanebit - 1ULL));
                if (slot < K_) buf[slot] = cb * 512 + u * 64 + lane;
            }
            filled += __popcll(mk[u]);
        }
    }
    __syncthreads();
    if (lane < K_) {
        int first = (filled > 0) ? buf[0] : 0;
        int v = (lane < filled) ? buf[lane] : first;
        widx[(size_t)wave * K_ + lane] = v;
    }
}

// ---------------------------------------------------------------------------
// Kernel 3: MLP via MFMA, B-in-registers. One block per (g, m-pair): 4096
// blocks, 256 thr (4 waves). Wave = (m_local, N-half): 6 M-tiles x 4 N-tiles,
// 96 MFMA. B-frags (Wm hi/lo, plain layout) loaded global->reg at entry; only
// A (h1, 24 KB) staged in LDS (XOR-swizzled). Outputs packed via 1 KB LDS ->
// coalesced float2 stores.
// ---------------------------------------------------------------------------
__global__ __launch_bounds__(256, 2) void mlp_kernel(const float* __restrict__ xyzs,
                                                     const float* __restrict__ Wd,
                                                     const short* __restrict__ Bhi_g,
                                                     const short* __restrict__ Blo_g,
                                                     const float* __restrict__ anchors,
                                                     const int* __restrict__ widx,
                                                     float* __restrict__ out_feat)
{
    const int t   = threadIdx.x;
    const int blk = blockIdx.x;          // G * 64
    const int g   = blk >> 6;
    const int m0  = (blk & 63) * 2;
    const int b = g >> 4, f = g & 15;

    const int lane = t & 63;
    const int w    = t >> 6;             // 0..3
    const int wml  = w & 1;              // m_local
    const int wn   = w >> 1;             // N-half (64 cols)
    const int row0 = lane & 15;
    const int kg   = lane >> 4;

    __shared__ __align__(16) short Ahi[192 * C0_];   // 24 KB
    __shared__ float wd_s[C0_ * 4];                  // 1 KB
    __shared__ float pmf[2][C1_];                    // 1 KB

    // --- B fragments from global (plain layout), issued immediately.
    short8 bh[4][2], bl[4][2];   // [nt][ks]
#pragma unroll
    for (int nt = 0; nt < 4; ++nt) {
        int o = wn * 64 + nt * 16 + row0;
#pragma unroll
        for (int ks = 0; ks < 2; ++ks) {
            int off = o * C0_ + (ks * 4 + kg) * 8;
            bh[nt][ks] = *reinterpret_cast<const short8*>(&Bhi_g[off]);
            bl[nt][ks] = *reinterpret_cast<const short8*>(&Blo_g[off]);
        }
    }

    wd_s[t] = Wd[t];

    // --- gather: thread t < 192 owns row t = ml*96 + dti*32 + k.
    float dx = 0.f, dy = 0.f, dz = 0.f, dt4 = 0.f;
    if (t < 192) {
        int ml  = (t >= 96) ? 1 : 0;
        int rr  = t - ml * 96;
        int dti = rr >> 5, k = rr & 31;
        int m   = m0 + ml;
        int tn  = 2 * f + dti - 1;
        if (tn < 0) tn = 0;
        const float* nb = xyzs + ((size_t)(b * T_ + tn) * N_) * 3;
        int idx = widx[((size_t)(g * 3 + dti) * M_ + m) * K_ + k];
        const float* aw = anchors + ((size_t)g * M_ + m) * 3;
        dx = nb[idx * 3 + 0] - aw[0];
        dy = nb[idx * 3 + 1] - aw[1];
        dz = nb[idx * 3 + 2] - aw[2];
        dt4 = (float)(dti - 1);
    }
    __syncthreads();   // wd_s ready

    // --- h1 = relu(Wd . d4) -> bf16, XOR-swizzled LDS rows.
    if (t < 192) {
#pragma unroll
        for (int u = 0; u < 8; ++u) {
            short8 hv;
#pragma unroll
            for (int e = 0; e < 8; ++e) {
                float4 wv = *reinterpret_cast<const float4*>(&wd_s[(u * 8 + e) * 4]);
                float s = dx * wv.x + dy * wv.y + dz * wv.z + dt4 * wv.w;
                hv[e] = f2bf(fmaxf(s, 0.0f));
            }
            *reinterpret_cast<short8*>(&Ahi[t * C0_ + ((u ^ (t & 7)) << 3)]) = hv;
        }
    }
    __syncthreads();

    // --- MFMA: D[rows 96 of wml][cols 64 of wn].
    f32x4 acc[6][4];
#pragma unroll
    for (int mt = 0; mt < 6; ++mt)
#pragma unroll
        for (int nt = 0; nt < 4; ++nt) {
            acc[mt][nt][0] = 0.f; acc[mt][nt][1] = 0.f;
            acc[mt][nt][2] = 0.f; acc[mt][nt][3] = 0.f;
        }

#pragma unroll
    for (int ks = 0; ks < 2; ++ks) {
        int chunk = ks * 4 + kg;
        short8 ah[6];
#pragma unroll
        for (int mt = 0; mt < 6; ++mt) {
            int r = wml * 96 + mt * 16 + row0;
            ah[mt] = *reinterpret_cast<const short8*>(&Ahi[r * C0_ + ((chunk ^ (r & 7)) << 3)]);
        }
#pragma unroll
        for (int mt = 0; mt < 6; ++mt)
#pragma unroll
            for (int nt = 0; nt < 4; ++nt) {
                acc[mt][nt] = __builtin_amdgcn_mfma_f32_16x16x32_bf16(ah[mt], bh[nt][ks], acc[mt][nt], 0, 0, 0);
                acc[mt][nt] = __builtin_amdgcn_mfma_f32_16x16x32_bf16(ah[mt], bl[nt][ks], acc[mt][nt], 0, 0, 0);
            }
    }

    // --- epilogue: per (dti, col) max over 32 k-rows (2 tiles x 4 regs x
    //     4 lane-groups), relu, sum dts; pack both m's -> float2 stores.
#pragma unroll
    for (int nt = 0; nt < 4; ++nt) {
        float fs = 0.f;
#pragma unroll
        for (int dti = 0; dti < 3; ++dti) {
            f32x4 a0 = acc[dti * 2 + 0][nt];
            f32x4 a1 = acc[dti * 2 + 1][nt];
            float mv = fmaxf(fmaxf(fmaxf(a0[0], a0[1]), fmaxf(a0[2], a0[3])),
                             fmaxf(fmaxf(a1[0], a1[1]), fmaxf(a1[2], a1[3])));
            mv = fmaxf(mv, 0.0f);
            mv = fmaxf(mv, __shfl_xor(mv, 16));
            mv = fmaxf(mv, __shfl_xor(mv, 32));
            fs += mv;   // dt order -1,0,+1 = reference accumulation order
        }
        if (lane < 16) pmf[wml][wn * 64 + nt * 16 + lane] = fs;
    }
    __syncthreads();

    if (t < C1_) {
        float2 v = make_float2(pmf[0][t], pmf[1][t]);
        *reinterpret_cast<float2*>(&out_feat[((size_t)g * C1_ + t) * M_ + m0]) = v;
    }
}

// ---------------------------------------------------------------------------
extern "C" void kernel_launch(void* const* d_in, const int* in_sizes, int n_in,
                              void* d_out, int out_size, void* d_ws, size_t ws_size,
                              hipStream_t stream)
{
    (void)in_sizes; (void)n_in; (void)out_size; (void)ws_size;
    const float* xyzs = (const float*)d_in[0];
    const float* Wd   = (const float*)d_in[1];
    const float* Wm   = (const float*)d_in[2];
    float* out = (float*)d_out;

    char* ws = (char*)d_ws;
    short* Bhi_g   = (short*)ws;                              // 16 KB
    short* Blo_g   = (short*)(ws + 16384);                    // 16 KB
    float* anchors = (float*)(ws + 32768);                    // G*M*3 floats
    int*   widx    = (int*)(ws + 32768 + (size_t)G_ * M_ * 3 * 4);

    float* out_xyz  = out;                 // (B,F,M,3) = (G,M,3)
    float* out_feat = out + G_ * M_ * 3;   // (B,F,C1,M) = (G,C1,M)

    hipLaunchKernelGGL(fps_kernel,    dim3(G_ + 1),           dim3(1024), 0, stream,
                       xyzs, anchors, out_xyz, Wm, Bhi_g, Blo_g);
    hipLaunchKernelGGL(ballq_kernel,  dim3(G_ * 3 * M_ / 4),  dim3(256), 0, stream, xyzs, anchors, widx);
    hipLaunchKernelGGL(mlp_kernel,    dim3(G_ * 64),          dim3(256), 0, stream,
                       xyzs, Wd, Bhi_g, Blo_g, anchors, widx, out_feat);
}

// Round 8
// 324.441 us; speedup vs baseline: 1.1084x; 1.1084x over previous
//
#include <hip/hip_runtime.h>
#include <stdint.h>

#define B_   4
#define T_   32
#define N_   4096
#define F_   16
#define G_   64      // B*F
#define M_   128
#define K_   32
#define C0_  64
#define C1_  128

typedef short  short8 __attribute__((ext_vector_type(8)));
typedef float  f32x4  __attribute__((ext_vector_type(4)));

static __device__ __forceinline__ short f2bf(float x) {
    union { float f; unsigned u; } v; v.f = x;
    unsigned r = (v.u + 0x7FFFu + ((v.u >> 16) & 1u)) >> 16;
    return (short)r;
}
static __device__ __forceinline__ float bf2f(short h) {
    union { float f; unsigned u; } v; v.u = ((unsigned)(unsigned short)h) << 16;
    return v.f;
}

// ---------------------------------------------------------------------------
// Kernel 1: FPS (blocks 0..63, 512 thr) + Wm hi/lo split (block 64).
// R4-proven structure: 512 threads (2 waves/SIMD -> stall covering), 8
// pts/thread, u64-key (bits(d)<<32 | 4095-i) shfl_xor butterfly (LDS pipe,
// pipelined; NOT DPP -- R6/R7 showed DPP chains serialize on VALU).
// One tweak vs R4: winner lane publishes key+coords to the per-wave entry
// (coord extraction depends only on pre-reduce bi -> hides under shfl
// latency); kills the dependent coord-cache fetch and the 48 KB cache.
// Bit-exact fp32 (contract off, reference eval order); strict u64 max ==
// first-occurrence argmax (index field unique per lane).
// ---------------------------------------------------------------------------
__global__ __launch_bounds__(512) void fps_kernel(const float* __restrict__ xyzs,
                                                  float* __restrict__ anchors,
                                                  float* __restrict__ out_xyz,
                                                  const float* __restrict__ Wm,
                                                  short* __restrict__ Bhi_g,
                                                  short* __restrict__ Blo_g)
{
#pragma clang fp contract(off)
    if (blockIdx.x >= G_) {
        // ---- Wm split role: 1 block x 512 threads x 2 tasks ----
#pragma unroll
        for (int rep = 0; rep < 2; ++rep) {
            int id = rep * 512 + threadIdx.x;   // 0..1023
            int o = id >> 3, c = id & 7;
            const float* wp = Wm + o * C0_ + c * 8;
            short8 hv, lv;
#pragma unroll
            for (int e = 0; e < 8; ++e) {
                float v = wp[e];
                short h = f2bf(v);
                short l = f2bf(v - bf2f(h));
                hv[e] = h; lv[e] = l;
            }
            int dst = o * C0_ + c * 8;
            *reinterpret_cast<short8*>(&Bhi_g[dst]) = hv;
            *reinterpret_cast<short8*>(&Blo_g[dst]) = lv;
        }
        return;
    }

    const int g = blockIdx.x;
    const int b = g >> 4, f = g & 15;
    const float* base = xyzs + ((size_t)(b * T_ + 2 * f) * N_) * 3;
    const int t = threadIdx.x;       // 0..511
    const int lane = t & 63;
    const int wid = t >> 6;          // 0..7

    __shared__ unsigned long long skey[2][8];
    __shared__ __align__(16) float4 scrd[2][8];

    float x[8], y[8], z[8], dist[8];
#pragma unroll
    for (int j = 0; j < 8; ++j) {
        int p = j * 512 + t;
        x[j] = base[p * 3 + 0];
        y[j] = base[p * 3 + 1];
        z[j] = base[p * 3 + 2];
        dist[j] = 1e10f;
    }

    float px = base[0], py = base[1], pz = base[2];   // anchor 0 = point 0
    float rx = 0.f, ry = 0.f, rz = 0.f;               // my buffered anchor
    if (t == 0) { rx = px; ry = py; rz = pz; }

    for (int it = 1; it < M_; ++it) {
        float bd = -1.0f; int bi = 0;
#pragma unroll
        for (int j = 0; j < 8; ++j) {
            float dx = x[j] - px;
            float dy = y[j] - py;
            float dz = z[j] - pz;
            float d = dx * dx + dy * dy;    // contract off: plain mul/add
            d = d + dz * dz;
            float nd = fminf(dist[j], d);
            dist[j] = nd;
            if (nd > bd) { bd = nd; bi = j * 512 + t; }  // ascending p: first max kept
        }
        unsigned long long mykey =
            ((unsigned long long)__float_as_uint(bd) << 32) | (unsigned)(N_ - 1 - bi);
        // candidate coords (depends only on bi -> scheduler hides it under
        // the shfl chain below)
        float cx = x[0], cy = y[0], cz = z[0];
#pragma unroll
        for (int j = 1; j < 8; ++j) {
            if (bi == j * 512 + t) { cx = x[j]; cy = y[j]; cz = z[j]; }
        }
        // 6-step u64 butterfly (LDS-pipe shfls, pipelined)
        unsigned long long key = mykey, k2;
#pragma unroll
        for (int off = 32; off > 0; off >>= 1) {
            k2 = __shfl_xor(key, off);
            key = (k2 > key) ? k2 : key;
        }
        const int par = it & 1;
        if (mykey == key) {                 // exactly one lane per wave
            skey[par][wid] = key;
            scrd[par][wid] = make_float4(cx, cy, cz, 0.f);
        }
        __syncthreads();
        unsigned long long ck = skey[par][0];
        float4 cc = scrd[par][0];
#pragma unroll
        for (int w = 1; w < 8; ++w) {
            unsigned long long ok = skey[par][w];
            float4 oc = scrd[par][w];
            if (ok > ck) { ck = ok; cc = oc; }
        }
        px = cc.x; py = cc.y; pz = cc.z;
        if (t == it) { rx = px; ry = py; rz = pz; }
    }

    if (t < M_) {
        size_t ao = ((size_t)g * M_ + t) * 3;
        anchors[ao + 0] = rx; anchors[ao + 1] = ry; anchors[ao + 2] = rz;
        out_xyz[ao + 0] = rx; out_xyz[ao + 1] = ry; out_xyz[ao + 2] = rz;
    }
}

// ---------------------------------------------------------------------------
// Kernel 2: Ball query, chunked. One wave per (g, dt, m). 8 iterations' loads
// + ballots issued together (pipelined), then VALU-only prefix-pack; exit
// check per chunk. Semantics identical to first-K-in-radius + fill.
// ---------------------------------------------------------------------------
__global__ __launch_bounds__(256) void ballq_kernel(const float* __restrict__ xyzs,
                                                    const float* __restrict__ anchors,
                                                    int* __restrict__ widx)
{
#pragma clang fp contract(off)
    const float R2 = 0.0225f;
    const int wave = (blockIdx.x << 2) + (threadIdx.x >> 6);
    const int lane = threadIdx.x & 63;
    const int m   = wave % M_;
    const int gd  = wave / M_;      // g*3 + dti
    const int dti = gd % 3;
    const int g   = gd / 3;
    const int b = g >> 4, f = g & 15;
    int tn = 2 * f + dti - 1;
    if (tn < 0) tn = 0;
    const float* nb = xyzs + ((size_t)(b * T_ + tn) * N_) * 3;
    const float* aw = anchors + ((size_t)g * M_ + m) * 3;
    const float ax = aw[0], ay = aw[1], az = aw[2];

    __shared__ int sbuf[4][K_];
    int* buf = sbuf[threadIdx.x >> 6];
    const unsigned long long lanebit = 1ULL << lane;

    int filled = 0;
    for (int cb = 0; cb < 8 && filled < K_; ++cb) {
        unsigned long long mk[8];
#pragma unroll
        for (int u = 0; u < 8; ++u) {
            int p = cb * 512 + u * 64 + lane;
            float dx = nb[p * 3 + 0] - ax;
            float dy = nb[p * 3 + 1] - ay;
            float dz = nb[p * 3 + 2] - az;
            float d2 = dx * dx + dy * dy;
            d2 = d2 + dz * dz;
            mk[u] = __ballot(d2 < R2);
        }
#pragma unroll
        for (int u = 0; u < 8; ++u) {
            if (mk[u] & lanebit) {
                int slot = filled + __popcll(mk[u] & (lanebit - 1ULL));
                if (slot < K_) buf[slot] = cb * 512 + u * 64 + lane;
            }
            filled += __popcll(mk[u]);
        }
    }
    __syncthreads();
    if (lane < K_) {
        int first = (filled > 0) ? buf[0] : 0;
        int v = (lane < filled) ? buf[lane] : first;
        widx[(size_t)wave * K_ + lane] = v;
    }
}

// ---------------------------------------------------------------------------
// Kernel 3: MLP via MFMA, B-in-registers. One block per (g, m-pair): 4096
// blocks, 256 thr (4 waves). Wave = (m_local, N-half): 6 M-tiles x 4 N-tiles,
// 96 MFMA. B-frags (Wm hi/lo, plain layout) loaded global->reg at entry; only
// A (h1, 24 KB) staged in LDS (XOR-swizzled). Outputs packed via 1 KB LDS ->
// coalesced float2 stores.
// ---------------------------------------------------------------------------
__global__ __launch_bounds__(256, 2) void mlp_kernel(const float* __restrict__ xyzs,
                                                     const float* __restrict__ Wd,
                                                     const short* __restrict__ Bhi_g,
                                                     const short* __restrict__ Blo_g,
                                                     const float* __restrict__ anchors,
                                                     const int* __restrict__ widx,
                                                     float* __restrict__ out_feat)
{
    const int t   = threadIdx.x;
    const int blk = blockIdx.x;          // G * 64
    const int g   = blk >> 6;
    const int m0  = (blk & 63) * 2;
    const int b = g >> 4, f = g & 15;

    const int lane = t & 63;
    const int w    = t >> 6;             // 0..3
    const int wml  = w & 1;              // m_local
    const int wn   = w >> 1;             // N-half (64 cols)
    const int row0 = lane & 15;
    const int kg   = lane >> 4;

    __shared__ __align__(16) short Ahi[192 * C0_];   // 24 KB
    __shared__ float wd_s[C0_ * 4];                  // 1 KB
    __shared__ float pmf[2][C1_];                    // 1 KB

    // --- B fragments from global (plain layout), issued immediately.
    short8 bh[4][2], bl[4][2];   // [nt][ks]
#pragma unroll
    for (int nt = 0; nt < 4; ++nt) {
        int o = wn * 64 + nt * 16 + row0;
#pragma unroll
        for (int ks = 0; ks < 2; ++ks) {
            int off = o * C0_ + (ks * 4 + kg) * 8;
            bh[nt][ks] = *reinterpret_cast<const short8*>(&Bhi_g[off]);
            bl[nt][ks] = *reinterpret_cast<const short8*>(&Blo_g[off]);
        }
    }

    wd_s[t] = Wd[t];

    // --- gather: thread t < 192 owns row t = ml*96 + dti*32 + k.
    float dx = 0.f, dy = 0.f, dz = 0.f, dt4 = 0.f;
    if (t < 192) {
        int ml  = (t >= 96) ? 1 : 0;
        int rr  = t - ml * 96;
        int dti = rr >> 5, k = rr & 31;
        int m   = m0 + ml;
        int tn  = 2 * f + dti - 1;
        if (tn < 0) tn = 0;
        const float* nb = xyzs + ((size_t)(b * T_ + tn) * N_) * 3;
        int idx = widx[((size_t)(g * 3 + dti) * M_ + m) * K_ + k];
        const float* aw = anchors + ((size_t)g * M_ + m) * 3;
        dx = nb[idx * 3 + 0] - aw[0];
        dy = nb[idx * 3 + 1] - aw[1];
        dz = nb[idx * 3 + 2] - aw[2];
        dt4 = (float)(dti - 1);
    }
    __syncthreads();   // wd_s ready

    // --- h1 = relu(Wd . d4) -> bf16, XOR-swizzled LDS rows.
    if (t < 192) {
#pragma unroll
        for (int u = 0; u < 8; ++u) {
            short8 hv;
#pragma unroll
            for (int e = 0; e < 8; ++e) {
                float4 wv = *reinterpret_cast<const float4*>(&wd_s[(u * 8 + e) * 4]);
                float s = dx * wv.x + dy * wv.y + dz * wv.z + dt4 * wv.w;
                hv[e] = f2bf(fmaxf(s, 0.0f));
            }
            *reinterpret_cast<short8*>(&Ahi[t * C0_ + ((u ^ (t & 7)) << 3)]) = hv;
        }
    }
    __syncthreads();

    // --- MFMA: D[rows 96 of wml][cols 64 of wn].
    f32x4 acc[6][4];
#pragma unroll
    for (int mt = 0; mt < 6; ++mt)
#pragma unroll
        for (int nt = 0; nt < 4; ++nt) {
            acc[mt][nt][0] = 0.f; acc[mt][nt][1] = 0.f;
            acc[mt][nt][2] = 0.f; acc[mt][nt][3] = 0.f;
        }

#pragma unroll
    for (int ks = 0; ks < 2; ++ks) {
        int chunk = ks * 4 + kg;
        short8 ah[6];
#pragma unroll
        for (int mt = 0; mt < 6; ++mt) {
            int r = wml * 96 + mt * 16 + row0;
            ah[mt] = *reinterpret_cast<const short8*>(&Ahi[r * C0_ + ((chunk ^ (r & 7)) << 3)]);
        }
#pragma unroll
        for (int mt = 0; mt < 6; ++mt)
#pragma unroll
            for (int nt = 0; nt < 4; ++nt) {
                acc[mt][nt] = __builtin_amdgcn_mfma_f32_16x16x32_bf16(ah[mt], bh[nt][ks], acc[mt][nt], 0, 0, 0);
                acc[mt][nt] = __builtin_amdgcn_mfma_f32_16x16x32_bf16(ah[mt], bl[nt][ks], acc[mt][nt], 0, 0, 0);
            }
    }

    // --- epilogue: per (dti, col) max over 32 k-rows (2 tiles x 4 regs x
    //     4 lane-groups), relu, sum dts; pack both m's -> float2 stores.
#pragma unroll
    for (int nt = 0; nt < 4; ++nt) {
        float fs = 0.f;
#pragma unroll
        for (int dti = 0; dti < 3; ++dti) {
            f32x4 a0 = acc[dti * 2 + 0][nt];
            f32x4 a1 = acc[dti * 2 + 1][nt];
            float mv = fmaxf(fmaxf(fmaxf(a0[0], a0[1]), fmaxf(a0[2], a0[3])),
                             fmaxf(fmaxf(a1[0], a1[1]), fmaxf(a1[2], a1[3])));
            mv = fmaxf(mv, 0.0f);
            mv = fmaxf(mv, __shfl_xor(mv, 16));
            mv = fmaxf(mv, __shfl_xor(mv, 32));
            fs += mv;   // dt order -1,0,+1 = reference accumulation order
        }
        if (lane < 16) pmf[wml][wn * 64 + nt * 16 + lane] = fs;
    }
    __syncthreads();

    if (t < C1_) {
        float2 v = make_float2(pmf[0][t], pmf[1][t]);
        *reinterpret_cast<float2*>(&out_feat[((size_t)g * C1_ + t) * M_ + m0]) = v;
    }
}

// ---------------------------------------------------------------------------
extern "C" void kernel_launch(void* const* d_in, const int* in_sizes, int n_in,
                              void* d_out, int out_size, void* d_ws, size_t ws_size,
                              hipStream_t stream)
{
    (void)in_sizes; (void)n_in; (void)out_size; (void)ws_size;
    const float* xyzs = (const float*)d_in[0];
    const float* Wd   = (const float*)d_in[1];
    const float* Wm   = (const float*)d_in[2];
    float* out = (float*)d_out;

    char* ws = (char*)d_ws;
    short* Bhi_g   = (short*)ws;                              // 16 KB
    short* Blo_g   = (short*)(ws + 16384);                    // 16 KB
    float* anchors = (float*)(ws + 32768);                    // G*M*3 floats
    int*   widx    = (int*)(ws + 32768 + (size_t)G_ * M_ * 3 * 4);

    float* out_xyz  = out;                 // (B,F,M,3) = (G,M,3)
    float* out_feat = out + G_ * M_ * 3;   // (B,F,C1,M) = (G,C1,M)

    hipLaunchKernelGGL(fps_kernel,    dim3(G_ + 1),           dim3(512), 0, stream,
                       xyzs, anchors, out_xyz, Wm, Bhi_g, Blo_g);
    hipLaunchKernelGGL(ballq_kernel,  dim3(G_ * 3 * M_ / 4),  dim3(256), 0, stream, xyzs, anchors, widx);
    hipLaunchKernelGGL(mlp_kernel,    dim3(G_ * 64),          dim3(256), 0, stream,
                       xyzs, Wd, Bhi_g, Blo_g, anchors, widx, out_feat);
}

// Round 9
// 323.964 us; speedup vs baseline: 1.1101x; 1.0015x over previous
//
#include <hip/hip_runtime.h>
#include <stdint.h>

#define B_   4
#define T_   32
#define N_   4096
#define F_   16
#define G_   64      // B*F
#define M_   128
#define K_   32
#define C0_  64
#define C1_  128

typedef short  short8 __attribute__((ext_vector_type(8)));
typedef float  f32x4  __attribute__((ext_vector_type(4)));

static __device__ __forceinline__ short f2bf(float x) {
    union { float f; unsigned u; } v; v.f = x;
    unsigned r = (v.u + 0x7FFFu + ((v.u >> 16) & 1u)) >> 16;
    return (short)r;
}
static __device__ __forceinline__ float bf2f(short h) {
    union { float f; unsigned u; } v; v.u = ((unsigned)(unsigned short)h) << 16;
    return v.f;
}

// ---------------------------------------------------------------------------
// Kernel 1: FPS (blocks 0..63, 512 thr) + Wm hi/lo split (block 64).
// 512 threads (2 waves/SIMD), 8 pts/thread, u64-key shfl_xor butterfly.
// Cross-wave combine: each lane reads ONE of the 8 (key,coords) entries
// (parallel LDS), then 3-step shfl_xor butterfly over (key,x,y,z) -- replaces
// the R8 serial 16-load select chain (the measured +1300 cyc/iter).
// Bit-exact fp32 (contract off, reference eval order); strict u64 max ==
// first-occurrence argmax (index field unique per lane).
// ---------------------------------------------------------------------------
__global__ __launch_bounds__(512) void fps_kernel(const float* __restrict__ xyzs,
                                                  float* __restrict__ anchors,
                                                  float* __restrict__ out_xyz,
                                                  const float* __restrict__ Wm,
                                                  short* __restrict__ Bhi_g,
                                                  short* __restrict__ Blo_g)
{
#pragma clang fp contract(off)
    if (blockIdx.x >= G_) {
        // ---- Wm split role: 1 block x 512 threads x 2 tasks ----
#pragma unroll
        for (int rep = 0; rep < 2; ++rep) {
            int id = rep * 512 + threadIdx.x;   // 0..1023
            int o = id >> 3, c = id & 7;
            const float* wp = Wm + o * C0_ + c * 8;
            short8 hv, lv;
#pragma unroll
            for (int e = 0; e < 8; ++e) {
                float v = wp[e];
                short h = f2bf(v);
                short l = f2bf(v - bf2f(h));
                hv[e] = h; lv[e] = l;
            }
            int dst = o * C0_ + c * 8;
            *reinterpret_cast<short8*>(&Bhi_g[dst]) = hv;
            *reinterpret_cast<short8*>(&Blo_g[dst]) = lv;
        }
        return;
    }

    const int g = blockIdx.x;
    const int b = g >> 4, f = g & 15;
    const float* base = xyzs + ((size_t)(b * T_ + 2 * f) * N_) * 3;
    const int t = threadIdx.x;       // 0..511
    const int lane = t & 63;
    const int wid = t >> 6;          // 0..7

    __shared__ unsigned long long skey[2][8];
    __shared__ __align__(16) float4 scrd[2][8];

    float x[8], y[8], z[8], dist[8];
#pragma unroll
    for (int j = 0; j < 8; ++j) {
        int p = j * 512 + t;
        x[j] = base[p * 3 + 0];
        y[j] = base[p * 3 + 1];
        z[j] = base[p * 3 + 2];
        dist[j] = 1e10f;
    }

    float px = base[0], py = base[1], pz = base[2];   // anchor 0 = point 0
    float rx = 0.f, ry = 0.f, rz = 0.f;               // my buffered anchor
    if (t == 0) { rx = px; ry = py; rz = pz; }

    for (int it = 1; it < M_; ++it) {
        float bd = -1.0f; int bi = 0;
#pragma unroll
        for (int j = 0; j < 8; ++j) {
            float dx = x[j] - px;
            float dy = y[j] - py;
            float dz = z[j] - pz;
            float d = dx * dx + dy * dy;    // contract off: plain mul/add
            d = d + dz * dz;
            float nd = fminf(dist[j], d);
            dist[j] = nd;
            if (nd > bd) { bd = nd; bi = j * 512 + t; }  // ascending p: first max kept
        }
        unsigned long long mykey =
            ((unsigned long long)__float_as_uint(bd) << 32) | (unsigned)(N_ - 1 - bi);
        // candidate coords (depends only on bi -> hides under the shfl chain)
        float cx = x[0], cy = y[0], cz = z[0];
#pragma unroll
        for (int j = 1; j < 8; ++j) {
            if (bi == j * 512 + t) { cx = x[j]; cy = y[j]; cz = z[j]; }
        }
        // 6-step u64 butterfly (LDS-pipe shfls, pipelined)
        unsigned long long key = mykey, k2;
#pragma unroll
        for (int off = 32; off > 0; off >>= 1) {
            k2 = __shfl_xor(key, off);
            key = (k2 > key) ? k2 : key;
        }
        const int par = it & 1;
        if (mykey == key) {                 // exactly one lane per wave
            skey[par][wid] = key;
            scrd[par][wid] = make_float4(cx, cy, cz, 0.f);
        }
        __syncthreads();
        // parallel-lane combine: lane reads entry (lane&7), 3-step butterfly
        unsigned long long ck = skey[par][lane & 7];
        float4 cf = scrd[par][lane & 7];
        float kx = cf.x, ky = cf.y, kz = cf.z;
#pragma unroll
        for (int off = 1; off <= 4; off <<= 1) {
            unsigned long long ok = __shfl_xor(ck, off);
            float ox = __shfl_xor(kx, off);
            float oy = __shfl_xor(ky, off);
            float oz = __shfl_xor(kz, off);
            if (ok > ck) { ck = ok; kx = ox; ky = oy; kz = oz; }
        }
        px = kx; py = ky; pz = kz;          // all lanes: block max + coords
        if (t == it) { rx = px; ry = py; rz = pz; }
    }

    if (t < M_) {
        size_t ao = ((size_t)g * M_ + t) * 3;
        anchors[ao + 0] = rx; anchors[ao + 1] = ry; anchors[ao + 2] = rz;
        out_xyz[ao + 0] = rx; out_xyz[ao + 1] = ry; out_xyz[ao + 2] = rz;
    }
}

// ---------------------------------------------------------------------------
// Kernel 2: Ball query, chunked. One wave per (g, dt, m). 8 iterations' loads
// + ballots issued together (pipelined), then VALU-only prefix-pack; exit
// check per chunk. Semantics identical to first-K-in-radius + fill.
// ---------------------------------------------------------------------------
__global__ __launch_bounds__(256) void ballq_kernel(const float* __restrict__ xyzs,
                                                    const float* __restrict__ anchors,
                                                    int* __restrict__ widx)
{
#pragma clang fp contract(off)
    const float R2 = 0.0225f;
    const int wave = (blockIdx.x << 2) + (threadIdx.x >> 6);
    const int lane = threadIdx.x & 63;
    const int m   = wave % M_;
    const int gd  = wave / M_;      // g*3 + dti
    const int dti = gd % 3;
    const int g   = gd / 3;
    const int b = g >> 4, f = g & 15;
    int tn = 2 * f + dti - 1;
    if (tn < 0) tn = 0;
    const float* nb = xyzs + ((size_t)(b * T_ + tn) * N_) * 3;
    const float* aw = anchors + ((size_t)g * M_ + m) * 3;
    const float ax = aw[0], ay = aw[1], az = aw[2];

    __shared__ int sbuf[4][K_];
    int* buf = sbuf[threadIdx.x >> 6];
    const unsigned long long lanebit = 1ULL << lane;

    int filled = 0;
    for (int cb = 0; cb < 8 && filled < K_; ++cb) {
        unsigned long long mk[8];
#pragma unroll
        for (int u = 0; u < 8; ++u) {
            int p = cb * 512 + u * 64 + lane;
            float dx = nb[p * 3 + 0] - ax;
            float dy = nb[p * 3 + 1] - ay;
            float dz = nb[p * 3 + 2] - az;
            float d2 = dx * dx + dy * dy;
            d2 = d2 + dz * dz;
            mk[u] = __ballot(d2 < R2);
        }
#pragma unroll
        for (int u = 0; u < 8; ++u) {
            if (mk[u] & lanebit) {
                int slot = filled + __popcll(mk[u] & (lanebit - 1ULL));
                if (slot < K_) buf[slot] = cb * 512 + u * 64 + lane;
            }
            filled += __popcll(mk[u]);
        }
    }
    __syncthreads();
    if (lane < K_) {
        int first = (filled > 0) ? buf[0] : 0;
        int v = (lane < filled) ? buf[lane] : first;
        widx[(size_t)wave * K_ + lane] = v;
    }
}

// ---------------------------------------------------------------------------
// Kernel 3: MLP via MFMA, B-in-registers. One block per (g, m-pair): 4096
// blocks, 256 thr (4 waves). Wave = (m_local, N-half): 6 M-tiles x 4 N-tiles,
// 96 MFMA. B-frags (Wm hi/lo, plain layout) loaded global->reg at entry; only
// A (h1, 24 KB) staged in LDS (XOR-swizzled). Outputs packed via 1 KB LDS ->
// coalesced float2 stores.
// ---------------------------------------------------------------------------
__global__ __launch_bounds__(256, 2) void mlp_kernel(const float* __restrict__ xyzs,
                                                     const float* __restrict__ Wd,
                                                     const short* __restrict__ Bhi_g,
                                                     const short* __restrict__ Blo_g,
                                                     const float* __restrict__ anchors,
                                                     const int* __restrict__ widx,
                                                     float* __restrict__ out_feat)
{
    const int t   = threadIdx.x;
    const int blk = blockIdx.x;          // G * 64
    const int g   = blk >> 6;
    const int m0  = (blk & 63) * 2;
    const int b = g >> 4, f = g & 15;

    const int lane = t & 63;
    const int w    = t >> 6;             // 0..3
    const int wml  = w & 1;              // m_local
    const int wn   = w >> 1;             // N-half (64 cols)
    const int row0 = lane & 15;
    const int kg   = lane >> 4;

    __shared__ __align__(16) short Ahi[192 * C0_];   // 24 KB
    __shared__ float wd_s[C0_ * 4];                  // 1 KB
    __shared__ float pmf[2][C1_];                    // 1 KB

    // --- B fragments from global (plain layout), issued immediately.
    short8 bh[4][2], bl[4][2];   // [nt][ks]
#pragma unroll
    for (int nt = 0; nt < 4; ++nt) {
        int o = wn * 64 + nt * 16 + row0;
#pragma unroll
        for (int ks = 0; ks < 2; ++ks) {
            int off = o * C0_ + (ks * 4 + kg) * 8;
            bh[nt][ks] = *reinterpret_cast<const short8*>(&Bhi_g[off]);
            bl[nt][ks] = *reinterpret_cast<const short8*>(&Blo_g[off]);
        }
    }

    wd_s[t] = Wd[t];

    // --- gather: thread t < 192 owns row t = ml*96 + dti*32 + k.
    float dx = 0.f, dy = 0.f, dz = 0.f, dt4 = 0.f;
    if (t < 192) {
        int ml  = (t >= 96) ? 1 : 0;
        int rr  = t - ml * 96;
        int dti = rr >> 5, k = rr & 31;
        int m   = m0 + ml;
        int tn  = 2 * f + dti - 1;
        if (tn < 0) tn = 0;
        const float* nb = xyzs + ((size_t)(b * T_ + tn) * N_) * 3;
        int idx = widx[((size_t)(g * 3 + dti) * M_ + m) * K_ + k];
        const float* aw = anchors + ((size_t)g * M_ + m) * 3;
        dx = nb[idx * 3 + 0] - aw[0];
        dy = nb[idx * 3 + 1] - aw[1];
        dz = nb[idx * 3 + 2] - aw[2];
        dt4 = (float)(dti - 1);
    }
    __syncthreads();   // wd_s ready

    // --- h1 = relu(Wd . d4) -> bf16, XOR-swizzled LDS rows.
    if (t < 192) {
#pragma unroll
        for (int u = 0; u < 8; ++u) {
            short8 hv;
#pragma unroll
            for (int e = 0; e < 8; ++e) {
                float4 wv = *reinterpret_cast<const float4*>(&wd_s[(u * 8 + e) * 4]);
                float s = dx * wv.x + dy * wv.y + dz * wv.z + dt4 * wv.w;
                hv[e] = f2bf(fmaxf(s, 0.0f));
            }
            *reinterpret_cast<short8*>(&Ahi[t * C0_ + ((u ^ (t & 7)) << 3)]) = hv;
        }
    }
    __syncthreads();

    // --- MFMA: D[rows 96 of wml][cols 64 of wn].
    f32x4 acc[6][4];
#pragma unroll
    for (int mt = 0; mt < 6; ++mt)
#pragma unroll
        for (int nt = 0; nt < 4; ++nt) {
            acc[mt][nt][0] = 0.f; acc[mt][nt][1] = 0.f;
            acc[mt][nt][2] = 0.f; acc[mt][nt][3] = 0.f;
        }

#pragma unroll
    for (int ks = 0; ks < 2; ++ks) {
        int chunk = ks * 4 + kg;
        short8 ah[6];
#pragma unroll
        for (int mt = 0; mt < 6; ++mt) {
            int r = wml * 96 + mt * 16 + row0;
            ah[mt] = *reinterpret_cast<const short8*>(&Ahi[r * C0_ + ((chunk ^ (r & 7)) << 3)]);
        }
#pragma unroll
        for (int mt = 0; mt < 6; ++mt)
#pragma unroll
            for (int nt = 0; nt < 4; ++nt) {
                acc[mt][nt] = __builtin_amdgcn_mfma_f32_16x16x32_bf16(ah[mt], bh[nt][ks], acc[mt][nt], 0, 0, 0);
                acc[mt][nt] = __builtin_amdgcn_mfma_f32_16x16x32_bf16(ah[mt], bl[nt][ks], acc[mt][nt], 0, 0, 0);
            }
    }

    // --- epilogue: per (dti, col) max over 32 k-rows (2 tiles x 4 regs x
    //     4 lane-groups), relu, sum dts; pack both m's -> float2 stores.
#pragma unroll
    for (int nt = 0; nt < 4; ++nt) {
        float fs = 0.f;
#pragma unroll
        for (int dti = 0; dti < 3; ++dti) {
            f32x4 a0 = acc[dti * 2 + 0][nt];
            f32x4 a1 = acc[dti * 2 + 1][nt];
            float mv = fmaxf(fmaxf(fmaxf(a0[0], a0[1]), fmaxf(a0[2], a0[3])),
                             fmaxf(fmaxf(a1[0], a1[1]), fmaxf(a1[2], a1[3])));
            mv = fmaxf(mv, 0.0f);
            mv = fmaxf(mv, __shfl_xor(mv, 16));
            mv = fmaxf(mv, __shfl_xor(mv, 32));
            fs += mv;   // dt order -1,0,+1 = reference accumulation order
        }
        if (lane < 16) pmf[wml][wn * 64 + nt * 16 + lane] = fs;
    }
    __syncthreads();

    if (t < C1_) {
        float2 v = make_float2(pmf[0][t], pmf[1][t]);
        *reinterpret_cast<float2*>(&out_feat[((size_t)g * C1_ + t) * M_ + m0]) = v;
    }
}

// ---------------------------------------------------------------------------
extern "C" void kernel_launch(void* const* d_in, const int* in_sizes, int n_in,
                              void* d_out, int out_size, void* d_ws, size_t ws_size,
                              hipStream_t stream)
{
    (void)in_sizes; (void)n_in; (void)out_size; (void)ws_size;
    const float* xyzs = (const float*)d_in[0];
    const float* Wd   = (const float*)d_in[1];
    const float* Wm   = (const float*)d_in[2];
    float* out = (float*)d_out;

    char* ws = (char*)d_ws;
    short* Bhi_g   = (short*)ws;                              // 16 KB
    short* Blo_g   = (short*)(ws + 16384);                    // 16 KB
    float* anchors = (float*)(ws + 32768);                    // G*M*3 floats
    int*   widx    = (int*)(ws + 32768 + (size_t)G_ * M_ * 3 * 4);

    float* out_xyz  = out;                 // (B,F,M,3) = (G,M,3)
    float* out_feat = out + G_ * M_ * 3;   // (B,F,C1,M) = (G,C1,M)

    hipLaunchKernelGGL(fps_kernel,    dim3(G_ + 1),           dim3(512), 0, stream,
                       xyzs, anchors, out_xyz, Wm, Bhi_g, Blo_g);
    hipLaunchKernelGGL(ballq_kernel,  dim3(G_ * 3 * M_ / 4),  dim3(256), 0, stream, xyzs, anchors, widx);
    hipLaunchKernelGGL(mlp_kernel,    dim3(G_ * 64),          dim3(256), 0, stream,
                       xyzs, Wd, Bhi_g, Blo_g, anchors, widx, out_feat);
}